// Round 13
// baseline (247.836 us; speedup 1.0000x reference)
//
#include <hip/hip_runtime.h>

#define T_DIM 1024
#define B_DIM 16
#define D_DIM 512
#define K_W   31
#define PAD   15
#define ST    (B_DIM * D_DIM)

// ===========================================================================
// ALL numeric ops are f32 with NO fma contraction and numpy-sequential
// reduction order, to bit-match the harness's strict-sequential f32 np ref.
// Rounds 5-12 PASSED with absmax 0.0 — do NOT change rounding/order/precision:
// f64 accuracy FLIPS a borderline spike (rounds 1-4, absmax 0.998046875).
// R10 lesson: global fetches must consume full 128B lines (BK=32). R13 keeps
// BK=32 fetch granularity but splits LDS into 16-k half-buffers.
// ===========================================================================

// ---------------------------------------------------------------------------
// K1: pointwise GEMM, f32, strict d-ascending accumulation, no FMA.
// R13: half-buffer pipeline. Per 32-k tile (full-line global loads, same
// traffic as R9): stage k0..15 into slot A, barrier, compute A while writing
// slot B (k16..31, regs resident), barrier, compute B while loading tile+1
// and writing its slot A. LDS 35.3 KB -> 3 blocks/CU (launch_bounds 256,3;
// VGPR ~120), 12 waves/CU to cover the (now 32) barriers. R9 had 2 blocks/CU
// and 85% VALU-pipe occupancy — the 15% gap is barrier-edge stall this
// attacks. Compute order: slot A (k+0..15) then B (k+16..31), kk ascending
// -> accumulation order bit-identical to R9.
// ---------------------------------------------------------------------------
#define S_E 146
#define S_T 130
__global__ __launch_bounds__(256, 3)
void pw_gemm(const float* __restrict__ inp, const float* __restrict__ w_pw,
             const float* __restrict__ b_pw, float* __restrict__ Yw,
             int tau0, int tau1, int NTW)
{
#pragma clang fp contract(off)
    __shared__ float EsH[2][16 * S_E];   // [slot][k][skew(e_local)] 128 e
    __shared__ float TsH[2][16 * S_T];   // [slot][k][tau_local]     128 tau

    const int tid = threadIdx.x;
    const int e0  = blockIdx.x * 128;
    int tg0 = tau0 + blockIdx.y * 128;           // tau tile base
    if (tg0 + 128 > tau1) {                      // shift last tile; overlap
        int s = tau1 - 128;                      // writes identical values
        tg0 = (s > tau0) ? s : tau0;
    }
    const int b  = blockIdx.z;
    const int rt = tid >> 4;                     // tau-sub 0..15 (8 tau each)
    const int ce = tid & 15;                     // e-sub   0..15 (8 e each)
    const int eoff = ce * 8 + ((ce >> 2) << 2);  // skewed read base

    float acc[8][8];
#pragma unroll
    for (int i = 0; i < 8; ++i)
#pragma unroll
        for (int j = 0; j < 8; ++j) acc[i][j] = 0.0f;

    float4 avE[4], xvE[4], avO[4], xvO[4];

    // LOADT: full 32-k tile (128B-line granularity) into a register set.
#define LOADT(AV, XV, T)                                                     \
    {                                                                        \
        const int kbase = (T) * 32;                                          \
        _Pragma("unroll")                                                    \
        for (int i = 0; i < 4; ++i) {                                        \
            int cid = tid + 256 * i;                                         \
            int row = cid >> 3;                                              \
            int kq  = tid & 7;                                               \
            int trow = tg0 + row;                                            \
            if (trow > T_DIM - 1) trow = T_DIM - 1;                          \
            AV[i] = *(const float4*)&w_pw[(size_t)(e0 + row) * D_DIM         \
                                          + kbase + kq * 4];                 \
            XV[i] = *(const float4*)&inp[(size_t)trow * ST                   \
                                         + (size_t)b * D_DIM + kbase + kq * 4]; \
        }                                                                    \
    }

    // WRH: threads whose kq is in half H write their 16-k slice to slot H.
#define WRH(AV, XV, H)                                                       \
    if (((tid >> 2) & 1) == (H)) {                                           \
        _Pragma("unroll")                                                    \
        for (int i = 0; i < 4; ++i) {                                        \
            int cid = tid + 256 * i;                                         \
            int row = cid >> 3;                                              \
            int kq2 = tid & 3;                                               \
            int srow = row + ((row >> 5) << 2);   /* skew(e) */              \
            EsH[H][(kq2 * 4 + 0) * S_E + srow] = AV[i].x;                    \
            EsH[H][(kq2 * 4 + 1) * S_E + srow] = AV[i].y;                    \
            EsH[H][(kq2 * 4 + 2) * S_E + srow] = AV[i].z;                    \
            EsH[H][(kq2 * 4 + 3) * S_E + srow] = AV[i].w;                    \
            TsH[H][(kq2 * 4 + 0) * S_T + row] = XV[i].x;                     \
            TsH[H][(kq2 * 4 + 1) * S_T + row] = XV[i].y;                     \
            TsH[H][(kq2 * 4 + 2) * S_T + row] = XV[i].z;                     \
            TsH[H][(kq2 * 4 + 3) * S_T + row] = XV[i].w;                     \
        }                                                                    \
    }

    // CMP: 16 kk ascending from slot H (strict d order within the half).
#define CMP(H)                                                               \
    _Pragma("unroll 8")                                                      \
    for (int kk = 0; kk < 16; ++kk) {                                        \
        float4 tf0 = *(const float4*)&TsH[H][kk * S_T + rt * 8];             \
        float4 tf1 = *(const float4*)&TsH[H][kk * S_T + rt * 8 + 4];         \
        float4 ef0 = *(const float4*)&EsH[H][kk * S_E + eoff];               \
        float4 ef1 = *(const float4*)&EsH[H][kk * S_E + eoff + 4];           \
        float a[8] = {tf0.x, tf0.y, tf0.z, tf0.w, tf1.x, tf1.y, tf1.z, tf1.w}; \
        float x[8] = {ef0.x, ef0.y, ef0.z, ef0.w, ef1.x, ef1.y, ef1.z, ef1.w}; \
        _Pragma("unroll")                                                    \
        for (int i = 0; i < 8; ++i)                                          \
            _Pragma("unroll")                                                \
            for (int j = 0; j < 8; ++j)                                      \
                acc[i][j] = __fadd_rn(acc[i][j], __fmul_rn(a[i], x[j]));     \
    }

    // ---- prologue: tile 0 -> regs E, write its low half to slot 0
    LOADT(avE, xvE, 0);
    WRH(avE, xvE, 0);

    for (int it = 0; it < 16; it += 2) {
        // ---- even tile (regs E); tile it low half already in slot 0
        __syncthreads();                         // slot 0 ready
        LOADT(avO, xvO, it + 1);                 // next tile in flight
        CMP(0);                                  // k: it*32 + 0..15
        WRH(avE, xvE, 1);                        // stage k: it*32 + 16..31
        __syncthreads();                         // slot 1 ready
        CMP(1);                                  // k: it*32 + 16..31
        WRH(avO, xvO, 0);                        // stage tile it+1 low half

        // ---- odd tile (regs O)
        __syncthreads();                         // slot 0 ready
        if (it + 2 < 16) LOADT(avE, xvE, it + 2);
        CMP(0);                                  // k: (it+1)*32 + 0..15
        WRH(avO, xvO, 1);
        __syncthreads();                         // slot 1 ready
        CMP(1);                                  // k: (it+1)*32 + 16..31
        if (it + 2 < 16) WRH(avE, xvE, 0);
    }
#undef LOADT
#undef WRH
#undef CMP

    float bias[8];
#pragma unroll
    for (int j = 0; j < 8; ++j) bias[j] = b_pw[e0 + ce * 8 + j];

#pragma unroll
    for (int i = 0; i < 8; ++i) {
        int tau = tg0 + rt * 8 + i;
        if (tau < tau1) {
            float* yrow = Yw + ((size_t)b * NTW + (tau - tau0)) * D_DIM + e0 + ce * 8;
#pragma unroll
            for (int j = 0; j < 8; ++j)
                yrow[j] = __fadd_rn(acc[i][j], bias[j]);
        }
    }
}

// ---------------------------------------------------------------------------
// K2: FULLY FUSED depthwise conv + LIF scan + residual add.
// (byte-identical to round 12 — 64-step f32 warmup, bit-exact merge)
// ---------------------------------------------------------------------------
__global__ __launch_bounds__(64, 2)
void dwlif(const float* __restrict__ Yw, const float* __restrict__ w_dw,
           const float* __restrict__ inp, float* __restrict__ out,
           int t0p, int tau0, int NTW)
{
#pragma clang fp contract(off)
    const int lane  = threadIdx.x;
    const int d     = blockIdx.x * 64 + lane;    // 0..511
    const int chunk = blockIdx.y;                // chunk within pass
    const int b     = blockIdx.z;                // 0..15

    const int cstart = t0p + 128 * chunk;
    int ts = cstart - 64; if (ts < 0) ts = 0;    // warmup start (chunk0: 0)
    const int ngroups = (cstart == 0) ? 16 : 24; // (cstart+128 - ts) / 8
    const int outg    = ngroups - 16;            // first output group (even)

    float wd[K_W];
#pragma unroll
    for (int k = 0; k < K_W; ++k) wd[k] = w_dw[d * K_W + k];

    const float* __restrict__ ybase = Yw  + (size_t)b * NTW * D_DIM + d;
    const float* __restrict__ xbase = inp + (size_t)b * D_DIM + d;
    float*       __restrict__ obase = out + (size_t)b * D_DIM + d;

    auto YLD = [&](int tau) -> float {
        int idx = tau - tau0;
        idx = idx < 0 ? 0 : idx;
        idx = idx >= NTW ? NTW - 1 : idx;        // clamped addr, always valid
        float ld = ybase[(size_t)idx * D_DIM];
        return (tau >= 0 && tau < T_DIM) ? ld : 0.0f;   // zero-pad select
    };

    // window: yw[i] = y[tg - 15 + i] for current group base tg (i in [0,54))
    float yw[54], pf0[8], pf1[8], xq0[8], xq1[8];
#pragma unroll
    for (int i = 0; i < 54; ++i) yw[i] = YLD(ts - PAD + i);
#pragma unroll
    for (int j = 0; j < 8; ++j) pf0[j] = YLD(ts + 39 + j);
    if (outg == 0) {                             // chunk 0: group 0 emits
#pragma unroll
        for (int j = 0; j < 8; ++j) xq0[j] = xbase[(size_t)(ts + j) * ST];
    }

    float v = 0.0f;

#define GROUP(G_EXPR, PF_IN, PF_OUT, XQ_IN, XQ_OUT)                          \
    {                                                                        \
        const int g  = (G_EXPR);                                             \
        const int tg = ts + 8 * g;                                           \
        _Pragma("unroll")                                                    \
        for (int j = 0; j < 8; ++j) PF_OUT[j] = YLD(tg + 47 + j);            \
        if (g + 1 >= outg) {                     /* x for group g+1 */       \
            _Pragma("unroll")                                                \
            for (int j = 0; j < 8; ++j) {                                    \
                int tx = tg + 8 + j;                                         \
                tx = (tx > T_DIM - 1) ? T_DIM - 1 : tx;   /* tail clamp */   \
                XQ_OUT[j] = xbase[(size_t)tx * ST];                          \
            }                                                                \
        }                                                                    \
        _Pragma("unroll")                                                    \
        for (int s = 0; s < 8; ++s) {                                        \
            float z = 0.0f;                                                  \
            _Pragma("unroll")                                                \
            for (int k = 0; k < K_W; ++k)     /* strict ascending k */       \
                z = __fadd_rn(z, __fmul_rn(wd[k], yw[s + k]));               \
            v = __fadd_rn(__fmul_rn(v, 0.5f), z);                            \
            const bool sp = (v >= 1.0f);                                     \
            if (g >= outg)                                                   \
                obase[(size_t)(tg + s) * ST] =                               \
                    __fadd_rn(sp ? 1.0f : 0.0f, XQ_IN[s]);                   \
            v = sp ? 0.0f : v;                /* hard reset (detach) */      \
        }                                                                    \
        _Pragma("unroll")                                                    \
        for (int i = 0; i < 46; ++i) yw[i] = yw[i + 8];                      \
        _Pragma("unroll")                                                    \
        for (int j = 0; j < 8; ++j) yw[46 + j] = PF_IN[j];                   \
    }

    for (int it = 0; it < ngroups; it += 2) {
        GROUP(it,     pf0, pf1, xq0, xq1);
        GROUP(it + 1, pf1, pf0, xq1, xq0);
    }
#undef GROUP
}

// ---------------------------------------------------------------------------
// Driver: 2 kernels per pass. ws = Yw only (NTW rows of 32KB). L from
// ws_size (launch-time constant; R9/R11 rocprof confirmed L=1024 here).
// Pass tau window reaches t0-79 for the first chunk's warmup taps.
// ---------------------------------------------------------------------------
extern "C" void kernel_launch(void* const* d_in, const int* in_sizes, int n_in,
                              void* d_out, int out_size, void* d_ws, size_t ws_size,
                              hipStream_t stream)
{
    const float* inp  = (const float*)d_in[0];   // (T,B,D)
    const float* w_pw = (const float*)d_in[1];   // (D,D)
    const float* b_pw = (const float*)d_in[2];   // (D)
    const float* w_dw = (const float*)d_in[3];   // (D,K)
    float* out = (float*)d_out;

    auto need = [](int L) -> size_t {
        int ntw = (L + 94 > T_DIM) ? T_DIM : (L + 94);
        return (size_t)ntw * (ST * sizeof(float));
    };
    int L = 128;
    if      (ws_size >= need(1024)) L = 1024;
    else if (ws_size >= need(512))  L = 512;
    else if (ws_size >= need(256))  L = 256;

    float* Yw = (float*)d_ws;

    const int P = T_DIM / L;
    for (int p = 0; p < P; ++p) {
        const int t0   = p * L;
        const int t1   = t0 + L;
        const int tau0 = (t0 - 79 > 0) ? (t0 - 79) : 0;      // warmup halo
        const int tau1 = (t1 + PAD < T_DIM) ? (t1 + PAD) : T_DIM;
        const int NTW  = tau1 - tau0;

        dim3 g1(D_DIM / 128, (NTW + 127) / 128, B_DIM);
        pw_gemm<<<g1, 256, 0, stream>>>(inp, w_pw, b_pw, Yw, tau0, tau1, NTW);

        dim3 g2(D_DIM / 64, L / 128, B_DIM);
        dwlif<<<g2, 64, 0, stream>>>(Yw, w_dw, inp, out, t0, tau0, NTW);
    }
}

// Round 14
// 152.623 us; speedup vs baseline: 1.6238x; 1.6238x over previous
//
#include <hip/hip_runtime.h>

#define T_DIM 1024
#define B_DIM 16
#define D_DIM 512
#define K_W   31
#define PAD   15
#define ST    (B_DIM * D_DIM)

// ===========================================================================
// ALL numeric ops are f32 with NO fma contraction and numpy-sequential
// reduction order, to bit-match the harness's strict-sequential f32 np ref.
// Rounds 5-13 PASSED with absmax 0.0 — do NOT change rounding/order/precision:
// f64 accuracy FLIPS a borderline spike (rounds 1-4, absmax 0.998046875).
// GEMM geometry log: R9 structure = 128 us; R8 tile-split = 149; R10 BK=16 =
// 426 (L2 thrash, FETCH 8x); R13 half-buffer 3-block = 235 (FETCH +43%,
// WRITE +69%). R9's 2-block/CU BK=32 single-barrier layout is a narrow L2
// sweet spot — FROZEN. This file is the byte-level R12 revert (152.8 us).
// ===========================================================================

// ---------------------------------------------------------------------------
// K1: pointwise GEMM — byte-identical to ROUND 9 (128 us, 85% of the no-FMA
// VALU roofline): 128e x 128tau tile, BK=32 double-buffered LDS, one barrier
// per k0-step, prefetch before compute, S_E=146/S_T=130 (4*S = 8 mod 32 ->
// staging-write conflicts 2-way worst = free). FROZEN.
// ---------------------------------------------------------------------------
#define S_E 146
#define S_T 130
__global__ __launch_bounds__(256, 2)
void pw_gemm(const float* __restrict__ inp, const float* __restrict__ w_pw,
             const float* __restrict__ b_pw, float* __restrict__ Yw,
             int tau0, int tau1, int NTW)
{
#pragma clang fp contract(off)
    __shared__ float Es[2][32 * S_E];   // [buf][k][skew(e_local)] 128 e
    __shared__ float Ts[2][32 * S_T];   // [buf][k][tau_local]     128 tau

    const int tid = threadIdx.x;
    const int e0  = blockIdx.x * 128;
    int tg0 = tau0 + blockIdx.y * 128;           // tau tile base
    if (tg0 + 128 > tau1) {                      // shift last tile; overlap
        int s = tau1 - 128;                      // writes identical values
        tg0 = (s > tau0) ? s : tau0;
    }
    const int b  = blockIdx.z;
    const int rt = tid >> 4;                     // tau-sub 0..15 (8 tau each)
    const int ce = tid & 15;                     // e-sub   0..15 (8 e each)
    const int eoff = ce * 8 + ((ce >> 2) << 2);  // skewed read base

    float acc[8][8];
#pragma unroll
    for (int i = 0; i < 8; ++i)
#pragma unroll
        for (int j = 0; j < 8; ++j) acc[i][j] = 0.0f;

    float4 av[4], xv[4];

    // ---- prologue: load k0=0 tile and stage into buf 0
#pragma unroll
    for (int i = 0; i < 4; ++i) {
        int cid = tid + 256 * i;
        int row = cid >> 3;
        int kq  = cid & 7;
        int trow = tg0 + row;
        if (trow > T_DIM - 1) trow = T_DIM - 1;
        av[i] = *(const float4*)&w_pw[(size_t)(e0 + row) * D_DIM + kq * 4];
        xv[i] = *(const float4*)&inp[(size_t)trow * (B_DIM * D_DIM)
                                     + (size_t)b * D_DIM + kq * 4];
    }
#pragma unroll
    for (int i = 0; i < 4; ++i) {
        int cid = tid + 256 * i;
        int row = cid >> 3;
        int kq  = cid & 7;
        int srow = row + ((row >> 5) << 2);      // skew(e)
        Es[0][(kq * 4 + 0) * S_E + srow] = av[i].x;
        Es[0][(kq * 4 + 1) * S_E + srow] = av[i].y;
        Es[0][(kq * 4 + 2) * S_E + srow] = av[i].z;
        Es[0][(kq * 4 + 3) * S_E + srow] = av[i].w;
        Ts[0][(kq * 4 + 0) * S_T + row] = xv[i].x;
        Ts[0][(kq * 4 + 1) * S_T + row] = xv[i].y;
        Ts[0][(kq * 4 + 2) * S_T + row] = xv[i].z;
        Ts[0][(kq * 4 + 3) * S_T + row] = xv[i].w;
    }

    int cur = 0;
    for (int k0 = 0; k0 < D_DIM; k0 += 32) {     // strict ascending d blocks
        __syncthreads();                         // buf[cur] ready for all

        const bool has_next = (k0 + 32 < D_DIM);
        if (has_next) {                          // issue next tile's globals
#pragma unroll
            for (int i = 0; i < 4; ++i) {
                int cid = tid + 256 * i;
                int row = cid >> 3;
                int kq  = cid & 7;
                int trow = tg0 + row;
                if (trow > T_DIM - 1) trow = T_DIM - 1;
                av[i] = *(const float4*)&w_pw[(size_t)(e0 + row) * D_DIM
                                              + k0 + 32 + kq * 4];
                xv[i] = *(const float4*)&inp[(size_t)trow * (B_DIM * D_DIM)
                                             + (size_t)b * D_DIM + k0 + 32 + kq * 4];
            }
        }

#pragma unroll 8
        for (int kk = 0; kk < 32; ++kk) {        // strict ascending d
            float4 tf0 = *(const float4*)&Ts[cur][kk * S_T + rt * 8];
            float4 tf1 = *(const float4*)&Ts[cur][kk * S_T + rt * 8 + 4];
            float4 ef0 = *(const float4*)&Es[cur][kk * S_E + eoff];
            float4 ef1 = *(const float4*)&Es[cur][kk * S_E + eoff + 4];
            float a[8] = {tf0.x, tf0.y, tf0.z, tf0.w, tf1.x, tf1.y, tf1.z, tf1.w};
            float x[8] = {ef0.x, ef0.y, ef0.z, ef0.w, ef1.x, ef1.y, ef1.z, ef1.w};
#pragma unroll
            for (int i = 0; i < 8; ++i)
#pragma unroll
                for (int j = 0; j < 8; ++j)
                    acc[i][j] = __fadd_rn(acc[i][j], __fmul_rn(a[i], x[j]));
        }

        if (has_next) {                          // stage into the other buffer
            const int nxt = cur ^ 1;
#pragma unroll
            for (int i = 0; i < 4; ++i) {
                int cid = tid + 256 * i;
                int row = cid >> 3;
                int kq  = cid & 7;
                int srow = row + ((row >> 5) << 2);
                Es[nxt][(kq * 4 + 0) * S_E + srow] = av[i].x;
                Es[nxt][(kq * 4 + 1) * S_E + srow] = av[i].y;
                Es[nxt][(kq * 4 + 2) * S_E + srow] = av[i].z;
                Es[nxt][(kq * 4 + 3) * S_E + srow] = av[i].w;
                Ts[nxt][(kq * 4 + 0) * S_T + row] = xv[i].x;
                Ts[nxt][(kq * 4 + 1) * S_T + row] = xv[i].y;
                Ts[nxt][(kq * 4 + 2) * S_T + row] = xv[i].z;
                Ts[nxt][(kq * 4 + 3) * S_T + row] = xv[i].w;
            }
            cur = nxt;
        }
    }

    float bias[8];
#pragma unroll
    for (int j = 0; j < 8; ++j) bias[j] = b_pw[e0 + ce * 8 + j];

#pragma unroll
    for (int i = 0; i < 8; ++i) {
        int tau = tg0 + rt * 8 + i;
        if (tau < tau1) {
            float* yrow = Yw + ((size_t)b * NTW + (tau - tau0)) * D_DIM + e0 + ce * 8;
#pragma unroll
            for (int j = 0; j < 8; ++j)
                yrow[j] = __fadd_rn(acc[i][j], bias[j]);
        }
    }
}

// ---------------------------------------------------------------------------
// K2: FULLY FUSED depthwise conv + LIF scan + residual add.
// (byte-identical to round 12 — 64-step f32 warmup, bit-exact merge; runs
// at ~24 us ~= its memory floor: 64MB Y-reads incl. warmup re-reads + 33MB
// x + 33MB out at ~6 TB/s.)
// ---------------------------------------------------------------------------
__global__ __launch_bounds__(64, 2)
void dwlif(const float* __restrict__ Yw, const float* __restrict__ w_dw,
           const float* __restrict__ inp, float* __restrict__ out,
           int t0p, int tau0, int NTW)
{
#pragma clang fp contract(off)
    const int lane  = threadIdx.x;
    const int d     = blockIdx.x * 64 + lane;    // 0..511
    const int chunk = blockIdx.y;                // chunk within pass
    const int b     = blockIdx.z;                // 0..15

    const int cstart = t0p + 128 * chunk;
    int ts = cstart - 64; if (ts < 0) ts = 0;    // warmup start (chunk0: 0)
    const int ngroups = (cstart == 0) ? 16 : 24; // (cstart+128 - ts) / 8
    const int outg    = ngroups - 16;            // first output group (even)

    float wd[K_W];
#pragma unroll
    for (int k = 0; k < K_W; ++k) wd[k] = w_dw[d * K_W + k];

    const float* __restrict__ ybase = Yw  + (size_t)b * NTW * D_DIM + d;
    const float* __restrict__ xbase = inp + (size_t)b * D_DIM + d;
    float*       __restrict__ obase = out + (size_t)b * D_DIM + d;

    auto YLD = [&](int tau) -> float {
        int idx = tau - tau0;
        idx = idx < 0 ? 0 : idx;
        idx = idx >= NTW ? NTW - 1 : idx;        // clamped addr, always valid
        float ld = ybase[(size_t)idx * D_DIM];
        return (tau >= 0 && tau < T_DIM) ? ld : 0.0f;   // zero-pad select
    };

    // window: yw[i] = y[tg - 15 + i] for current group base tg (i in [0,54))
    float yw[54], pf0[8], pf1[8], xq0[8], xq1[8];
#pragma unroll
    for (int i = 0; i < 54; ++i) yw[i] = YLD(ts - PAD + i);
#pragma unroll
    for (int j = 0; j < 8; ++j) pf0[j] = YLD(ts + 39 + j);
    if (outg == 0) {                             // chunk 0: group 0 emits
#pragma unroll
        for (int j = 0; j < 8; ++j) xq0[j] = xbase[(size_t)(ts + j) * ST];
    }

    float v = 0.0f;

#define GROUP(G_EXPR, PF_IN, PF_OUT, XQ_IN, XQ_OUT)                          \
    {                                                                        \
        const int g  = (G_EXPR);                                             \
        const int tg = ts + 8 * g;                                           \
        _Pragma("unroll")                                                    \
        for (int j = 0; j < 8; ++j) PF_OUT[j] = YLD(tg + 47 + j);            \
        if (g + 1 >= outg) {                     /* x for group g+1 */       \
            _Pragma("unroll")                                                \
            for (int j = 0; j < 8; ++j) {                                    \
                int tx = tg + 8 + j;                                         \
                tx = (tx > T_DIM - 1) ? T_DIM - 1 : tx;   /* tail clamp */   \
                XQ_OUT[j] = xbase[(size_t)tx * ST];                          \
            }                                                                \
        }                                                                    \
        _Pragma("unroll")                                                    \
        for (int s = 0; s < 8; ++s) {                                        \
            float z = 0.0f;                                                  \
            _Pragma("unroll")                                                \
            for (int k = 0; k < K_W; ++k)     /* strict ascending k */       \
                z = __fadd_rn(z, __fmul_rn(wd[k], yw[s + k]));               \
            v = __fadd_rn(__fmul_rn(v, 0.5f), z);                            \
            const bool sp = (v >= 1.0f);                                     \
            if (g >= outg)                                                   \
                obase[(size_t)(tg + s) * ST] =                               \
                    __fadd_rn(sp ? 1.0f : 0.0f, XQ_IN[s]);                   \
            v = sp ? 0.0f : v;                /* hard reset (detach) */      \
        }                                                                    \
        _Pragma("unroll")                                                    \
        for (int i = 0; i < 46; ++i) yw[i] = yw[i + 8];                      \
        _Pragma("unroll")                                                    \
        for (int j = 0; j < 8; ++j) yw[46 + j] = PF_IN[j];                   \
    }

    for (int it = 0; it < ngroups; it += 2) {
        GROUP(it,     pf0, pf1, xq0, xq1);
        GROUP(it + 1, pf1, pf0, xq1, xq0);
    }
#undef GROUP
}

// ---------------------------------------------------------------------------
// Driver: 2 kernels per pass. ws = Yw only (NTW rows of 32KB). L from
// ws_size (launch-time constant; R9/R11 rocprof confirmed L=1024 here).
// Pass tau window reaches t0-79 for the first chunk's warmup taps.
// ---------------------------------------------------------------------------
extern "C" void kernel_launch(void* const* d_in, const int* in_sizes, int n_in,
                              void* d_out, int out_size, void* d_ws, size_t ws_size,
                              hipStream_t stream)
{
    const float* inp  = (const float*)d_in[0];   // (T,B,D)
    const float* w_pw = (const float*)d_in[1];   // (D,D)
    const float* b_pw = (const float*)d_in[2];   // (D)
    const float* w_dw = (const float*)d_in[3];   // (D,K)
    float* out = (float*)d_out;

    auto need = [](int L) -> size_t {
        int ntw = (L + 94 > T_DIM) ? T_DIM : (L + 94);
        return (size_t)ntw * (ST * sizeof(float));
    };
    int L = 128;
    if      (ws_size >= need(1024)) L = 1024;
    else if (ws_size >= need(512))  L = 512;
    else if (ws_size >= need(256))  L = 256;

    float* Yw = (float*)d_ws;

    const int P = T_DIM / L;
    for (int p = 0; p < P; ++p) {
        const int t0   = p * L;
        const int t1   = t0 + L;
        const int tau0 = (t0 - 79 > 0) ? (t0 - 79) : 0;      // warmup halo
        const int tau1 = (t1 + PAD < T_DIM) ? (t1 + PAD) : T_DIM;
        const int NTW  = tau1 - tau0;

        dim3 g1(D_DIM / 128, (NTW + 127) / 128, B_DIM);
        pw_gemm<<<g1, 256, 0, stream>>>(inp, w_pw, b_pw, Yw, tau0, tau1, NTW);

        dim3 g2(D_DIM / 64, L / 128, B_DIM);
        dwlif<<<g2, 64, 0, stream>>>(Yw, w_dw, inp, out, t0, tau0, NTW);
    }
}